// Round 2
// baseline (747.486 us; speedup 1.0000x reference)
//
#include <hip/hip_runtime.h>
#include <hip/hip_cooperative_groups.h>
#include <math.h>

namespace cg = cooperative_groups;

#define N_NODES 100000
#define D_FEAT  256
#define TOP_K   50000
#define NBINS   65536
#define NCHUNK  64          // NBINS / 1024 chunks for the parallel scan
#define CUTPOS  (N_NODES - TOP_K)
#define ROWSTRIDE 260       // 256 + 4 pad: bank = (4g + l + 8i) % 32 -> 2-way = free
#define GRID    1024        // 4 blocks/CU x 256 CU, guaranteed co-resident
#define EMIT_BLOCKS 640     // P5 split: emit ~103 MB vs edge ~64 MB -> 640/384
#define NBITW   3200        // member bitmask words (ceil(100000/32)=3125, padded)

// Workspace layout (byte offsets, all 16B-aligned):
//         0 : s32      float[N_NODES]   (400,000)
//   400,000 : ss       float[N_NODES]   (400,000)  bucket-sorted scores
//   800,000 : si       int[N_NODES]     (400,000)  bucket-sorted node ids
// 1,200,000 : hist     int[NBINS]       (262,144)  } contiguous: one zero region
// 1,462,144 : bits     uint[NBITW]      ( 12,800)  } member bitmask
// 1,562,144 : offs     int[NBINS]       (262,144)  chunk-LOCAL exclusive offsets
// 1,824,288 : cursor   int[NBINS]       (262,144)
// 2,086,432 : chunkSum int[NCHUNK]      (256)

__device__ __forceinline__ int bucket_of(float s) {
    int b = (int)(s * 65536.0f);
    return min(max(b, 0), NBINS - 1);
}

// numpy SIMD float32 exp (FMA universal-intrinsics path) — bit-exact, verified R6.
__device__ __forceinline__ float np_expf(float x) {
    float q  = rintf(x * 1.44269504088896341f);
    float xr = fmaf(-q, 0.693359375f, x);
    xr       = fmaf(-q, -2.12194440e-4f, xr);
    float x2 = xr * xr;
    float p  = 1.9875691500E-4f;
    p = fmaf(p, xr, 1.3981999507E-3f);
    p = fmaf(p, xr, 8.3334519073E-3f);
    p = fmaf(p, xr, 4.1665795894E-2f);
    p = fmaf(p, xr, 1.6666665459E-1f);
    p = fmaf(p, xr, 5.0000001201E-1f);
    p = fmaf(p, x2, xr);
    p = p + 1.0f;
    return ldexpf(p, (int)q);
}

// ---- phase bodies (shared by mega kernel and fallback kernels) ----

// OpenBLAS sgemv_t emulation, 8 lanes/node, bit-exact numerics. DO NOT TOUCH.
__device__ __forceinline__ void score_group(const float* __restrict__ h,
                                            float bval,
                                            float* __restrict__ s32,
                                            int* __restrict__ hist,
                                            float* rows,
                                            const float* wreg,
                                            int tid, int grp) {
    int wave = tid >> 6;
    int lane = tid & 63;
    int g    = lane >> 3;
    int l    = lane & 7;
    int nodeBase = grp * 32 + wave * 8;

    __syncthreads();   // prior iteration's readers done before overwrite
#pragma unroll
    for (int r = 0; r < 8; ++r) {
        float4 v = ((const float4*)(h + (size_t)(nodeBase + r) * D_FEAT))[lane];
        *((float4*)&rows[(wave * 8 + r) * ROWSTRIDE + lane * 4]) = v;
    }
    __syncthreads();

    const float* myrow = &rows[(wave * 8 + g) * ROWSTRIDE];
    float acc = 0.0f;
#pragma unroll
    for (int i = 0; i < 32; ++i)
        acc = fmaf(myrow[i * 8 + l], wreg[i], acc);

    float b01 = acc + __shfl_xor(acc, 1, 64);
    float b23 = b01 + __shfl_xor(b01, 2, 64);
    float z   = b23 + __shfl_xor(b23, 4, 64);

    z = z + bval;
    float t = np_expf(-z);
    float s = 1.0f / (1.0f + t);       // IEEE f32 divide

    if (l == 0) {
        int node = nodeBase + g;
        s32[node] = s;
        atomicAdd(&hist[bucket_of(s)], 1);
    }
}

__device__ __forceinline__ void scan_chunk(const int* __restrict__ hist,
                                           int* __restrict__ offs,
                                           int* __restrict__ cursor,
                                           int* __restrict__ chunkSum,
                                           int* wsum, int cid, int tid) {
    int lane = tid & 63;
    int wid  = tid >> 6;
    int base = cid * 1024 + tid * 4;

    int4 hv = *((const int4*)(hist + base));
    int e1 = hv.x;
    int e2 = hv.x + hv.y;
    int e3 = e2 + hv.z;
    int tot = e3 + hv.w;

    int incl = tot;
#pragma unroll
    for (int d = 1; d < 64; d <<= 1) {
        int t = __shfl_up(incl, d, 64);
        if (lane >= d) incl += t;
    }
    if (lane == 63) wsum[wid] = incl;
    __syncthreads();
    int wbase = 0;
#pragma unroll
    for (int w = 0; w < 3; ++w)
        if (w < wid) wbase += wsum[w];

    int excl = wbase + (incl - tot);
    int4 ov = make_int4(excl, excl + e1, excl + e2, excl + e3);
    *((int4*)(offs + base))   = ov;
    *((int4*)(cursor + base)) = ov;
    if (tid == 255) chunkSum[cid] = excl + tot;
}

// wave-0: exclusive scan of chunk totals -> sbase[64] (LDS)
__device__ __forceinline__ void build_base(const int* __restrict__ chunkSum,
                                           int* sbase, int tid) {
    if (tid < 64) {
        int v = chunkSum[tid];
        int inc = v;
#pragma unroll
        for (int d = 1; d < 64; d <<= 1) {
            int t = __shfl_up(inc, d, 64);
            if (tid >= d) inc += t;
        }
        sbase[tid] = inc - v;
    }
}

__device__ __forceinline__ void scatter_node(const float* __restrict__ s32,
                                             int* __restrict__ cursor,
                                             const int* __restrict__ offs,
                                             const int* sbase,
                                             unsigned int* __restrict__ bits,
                                             float* __restrict__ ss,
                                             int* __restrict__ si, int i) {
    float s = s32[i];
    int b = bucket_of(s);
    int pos = atomicAdd(&cursor[b], 1);       // chunk-local position
    int gbase = sbase[b >> 10];
    int gpos = gbase + pos;
    ss[gpos] = s;
    si[gpos] = i;
    // bucket fully above the cut -> every element selected, mark member now
    if (gbase + offs[b] >= CUTPOS)
        atomicOr(&bits[(unsigned)i >> 5], 1u << (i & 31));
}

// insertion sort ascending by (s asc, idx desc) — reversed = lax.top_k order.
// Also marks members of the (single) boundary bucket suffix.
__device__ __forceinline__ void sort_bucket(const int* __restrict__ offs,
                                            const int* sbase,
                                            unsigned int* __restrict__ bits,
                                            float* __restrict__ ss,
                                            int* __restrict__ si, int b) {
    int s0 = sbase[b >> 10] + offs[b];
    int e  = (b == NBINS - 1) ? N_NODES : sbase[(b + 1) >> 10] + offs[b + 1];
    if (e <= CUTPOS) return;                  // entirely below cut: never read
    for (int i = s0 + 1; i < e; ++i) {
        float ks = ss[i];
        int   ki = si[i];
        int j = i - 1;
        while (j >= s0) {
            float ps = ss[j];
            int   pi = si[j];
            bool gt = (ps > ks) || (ps == ks && pi < ki);
            if (!gt) break;
            ss[j + 1] = ps;
            si[j + 1] = pi;
            --j;
        }
        ss[j + 1] = ks;
        si[j + 1] = ki;
    }
    if (s0 < CUTPOS) {                        // boundary bucket: mark suffix
        for (int i = CUTPOS; i < e; ++i) {
            int id = si[i];
            atomicOr(&bits[(unsigned)id >> 5], 1u << (id & 31));
        }
    }
}

__device__ __forceinline__ void emit_row(const float* __restrict__ h,
                                         const float* __restrict__ ss,
                                         const int* __restrict__ si,
                                         float* __restrict__ out_newh,
                                         float* __restrict__ out_ids,
                                         int row, int lane) {
    int p = N_NODES - 1 - row;
    int id  = si[p];                          // wave-uniform -> broadcast
    float s = ss[p];
    if (lane == 0) out_ids[row] = (float)id;
    const float4* hv = (const float4*)(h + (size_t)id * D_FEAT);
    float4 v = hv[lane];
    ((float4*)(out_newh + (size_t)row * D_FEAT))[lane] =
        make_float4(v.x * s, v.y * s, v.z * s, v.w * s);
}

__device__ __forceinline__ unsigned mem_bit(const unsigned int* __restrict__ bits,
                                            int s) {
    return (bits[(unsigned)s >> 5] >> (s & 31)) & 1u;
}

__device__ __forceinline__ void edge_pair(const int* __restrict__ ei,
                                          const unsigned int* __restrict__ bits,
                                          float* __restrict__ out_mask,
                                          int E, int flag, int k) {
    int i0 = 2 * k;
    int i1 = i0 + 1;
    if (i1 < E) {
        int s0, d0, s1, d1;
        if (flag) {                    // int64 storage: value in even dword
            int4 a  = ((const int4*)ei)[k];
            int4 bq = ((const int4*)(ei + 2 * (size_t)E))[k];
            s0 = a.x;  s1 = a.z;
            d0 = bq.x; d1 = bq.z;
        } else {                       // int32 storage
            int2 a  = ((const int2*)ei)[k];
            int2 bq = ((const int2*)(ei + (size_t)E))[k];
            s0 = a.x;  s1 = a.y;
            d0 = bq.x; d1 = bq.y;
        }
        bool ok0 = ((unsigned)s0 < (unsigned)N_NODES) &&
                   ((unsigned)d0 < (unsigned)N_NODES) &&
                   mem_bit(bits, s0) && mem_bit(bits, d0);
        bool ok1 = ((unsigned)s1 < (unsigned)N_NODES) &&
                   ((unsigned)d1 < (unsigned)N_NODES) &&
                   mem_bit(bits, s1) && mem_bit(bits, d1);
        ((float2*)out_mask)[k] = make_float2(ok0 ? 1.0f : 0.0f, ok1 ? 1.0f : 0.0f);
    } else {                           // odd-E tail (not hit for E=3.2M)
        int s0, d0;
        if (flag) { s0 = ei[2 * i0]; d0 = ei[2 * ((size_t)E + i0)]; }
        else      { s0 = ei[i0];     d0 = ei[(size_t)E + i0]; }
        bool ok0 = ((unsigned)s0 < (unsigned)N_NODES) &&
                   ((unsigned)d0 < (unsigned)N_NODES) &&
                   mem_bit(bits, s0) && mem_bit(bits, d0);
        out_mask[i0] = ok0 ? 1.0f : 0.0f;
    }
}

// ---- the cooperative mega-kernel: 6 phases, 5 grid syncs, 1 dispatch ----
__global__ __launch_bounds__(256, 4) void mega_kernel(
        const float* __restrict__ h, const float* __restrict__ W,
        const float* __restrict__ bvec, const int* __restrict__ ei, int E,
        float* __restrict__ s32, float* __restrict__ ss, int* __restrict__ si,
        int* __restrict__ hist, unsigned int* __restrict__ bits,
        int* __restrict__ offs, int* __restrict__ cursor,
        int* __restrict__ chunkSum,
        float* __restrict__ out_newh, float* __restrict__ out_ids,
        float* __restrict__ out_mask) {
    __shared__ float rows[32 * ROWSTRIDE];   // 33,280 B
    __shared__ float wl[256];
    __shared__ int   wsum[4];
    __shared__ int   sbase[64];
    __shared__ int   sflag;

    cg::grid_group grid = cg::this_grid();
    int tid  = threadIdx.x;
    int bid  = blockIdx.x;
    int gtid = bid * 256 + tid;

    // P0: zero hist + member bits (replaces host memset)
    if (gtid < NBINS) hist[gtid] = 0;
    if (gtid < NBITW) bits[gtid] = 0;

    // preload W chain-slice into registers
    wl[tid] = W[tid];
    __syncthreads();
    int l = tid & 7;
    float wreg[32];
#pragma unroll
    for (int i = 0; i < 32; ++i) wreg[i] = wl[i * 8 + l];
    float bval = bvec[0];

    grid.sync();

    // P1: score (grid-stride over 3125 groups of 32 nodes)
    for (int grp = bid; grp < N_NODES / 32; grp += GRID)
        score_group(h, bval, s32, hist, rows, wreg, tid, grp);

    grid.sync();

    // P2: chunk scan (blocks 0..63)
    if (bid < NCHUNK) scan_chunk(hist, offs, cursor, chunkSum, wsum, bid, tid);

    grid.sync();

    // P3: scatter + sure-member marking
    build_base(chunkSum, sbase, tid);
    __syncthreads();
    if (gtid < N_NODES) scatter_node(s32, cursor, offs, sbase, bits, ss, si, gtid);

    grid.sync();

    // P4: per-bucket sort + boundary member marking (sbase persists in LDS)
    if (gtid < NBINS) sort_bucket(offs, sbase, bits, ss, si, gtid);

    grid.sync();

    // P5: emit || edge — independent now that member is final
    int lane = tid & 63;
    if (bid < EMIT_BLOCKS) {
        int wgid = bid * 4 + (tid >> 6);
        for (int row = wgid; row < TOP_K; row += EMIT_BLOCKS * 4)
            emit_row(h, ss, si, out_newh, out_ids, row, lane);
    } else {
        if (tid < 64) {                       // int64-vs-int32 detect, wave 0
            int v = ei[2 * tid + 1];
            unsigned long long m = __ballot(v == 0);
            if (tid == 0) sflag = (m == ~0ULL) ? 1 : 0;
        }
        __syncthreads();
        int flag = sflag;
        int npairs = (E + 1) / 2;
        int t0 = (bid - EMIT_BLOCKS) * 256 + tid;
        for (int k = t0; k < npairs; k += (GRID - EMIT_BLOCKS) * 256)
            edge_pair(ei, bits, out_mask, E, flag, k);
    }
}

// ---- fallback path (taken only if cooperative launch is rejected) ----

__global__ void f_score(const float* __restrict__ h, const float* __restrict__ W,
                        const float* __restrict__ bvec,
                        float* __restrict__ s32, int* __restrict__ hist) {
    __shared__ float rows[32 * ROWSTRIDE];
    __shared__ float wl[256];
    int tid = threadIdx.x;
    wl[tid] = W[tid];
    __syncthreads();
    int l = tid & 7;
    float wreg[32];
#pragma unroll
    for (int i = 0; i < 32; ++i) wreg[i] = wl[i * 8 + l];
    score_group(h, bvec[0], s32, hist, rows, wreg, tid, blockIdx.x);
}

__global__ void f_scan(const int* __restrict__ hist, int* __restrict__ offs,
                       int* __restrict__ cursor, int* __restrict__ chunkSum) {
    __shared__ int wsum[4];
    scan_chunk(hist, offs, cursor, chunkSum, wsum, blockIdx.x, threadIdx.x);
}

__global__ void f_scatter(const float* __restrict__ s32, int* __restrict__ cursor,
                          const int* __restrict__ offs,
                          const int* __restrict__ chunkSum,
                          unsigned int* __restrict__ bits,
                          float* __restrict__ ss, int* __restrict__ si) {
    __shared__ int sbase[64];
    int tid = threadIdx.x;
    build_base(chunkSum, sbase, tid);
    __syncthreads();
    int i = blockIdx.x * 256 + tid;
    if (i < N_NODES) scatter_node(s32, cursor, offs, sbase, bits, ss, si, i);
}

__global__ void f_sort(const int* __restrict__ offs,
                       const int* __restrict__ chunkSum,
                       unsigned int* __restrict__ bits,
                       float* __restrict__ ss, int* __restrict__ si) {
    __shared__ int sbase[64];
    int tid = threadIdx.x;
    build_base(chunkSum, sbase, tid);
    __syncthreads();
    int b = blockIdx.x * 256 + tid;
    if (b < NBINS) sort_bucket(offs, sbase, bits, ss, si, b);
}

__global__ void f_emit(const float* __restrict__ h, const float* __restrict__ ss,
                       const int* __restrict__ si, float* __restrict__ out_newh,
                       float* __restrict__ out_ids) {
    int tid = threadIdx.x;
    int row = blockIdx.x * 4 + (tid >> 6);
    if (row < TOP_K) emit_row(h, ss, si, out_newh, out_ids, row, tid & 63);
}

__global__ void f_edge(const int* __restrict__ ei,
                       const unsigned int* __restrict__ bits,
                       float* __restrict__ out_mask, int E) {
    __shared__ int sflag;
    int tid = threadIdx.x;
    if (tid < 64) {
        int v = ei[2 * tid + 1];
        unsigned long long m = __ballot(v == 0);
        if (tid == 0) sflag = (m == ~0ULL) ? 1 : 0;
    }
    __syncthreads();
    int k = blockIdx.x * 256 + tid;
    if (k < (E + 1) / 2) edge_pair(ei, bits, out_mask, E, sflag, k);
}

extern "C" void kernel_launch(void* const* d_in, const int* in_sizes, int n_in,
                              void* d_out, int out_size, void* d_ws, size_t ws_size,
                              hipStream_t stream) {
    const float* h  = (const float*)d_in[0];
    const float* W  = (const float*)d_in[1];
    const float* bv = (const float*)d_in[2];
    const int*   ei = (const int*)d_in[3];
    int E = in_sizes[3] / 2;

    char* ws = (char*)d_ws;
    float*        s32      = (float*)(ws + 0);
    float*        ss       = (float*)(ws + 400000);
    int*          si       = (int*)(ws + 800000);
    int*          hist     = (int*)(ws + 1200000);
    unsigned int* bits     = (unsigned int*)(ws + 1462144);
    int*          offs     = (int*)(ws + 1562144);
    int*          cursor   = (int*)(ws + 1824288);
    int*          chunkSum = (int*)(ws + 2086432);

    float* out      = (float*)d_out;
    float* out_newh = out;                                  // TOP_K * D_FEAT
    float* out_ids  = out + (size_t)TOP_K * D_FEAT;         // TOP_K
    float* out_mask = out + (size_t)TOP_K * D_FEAT + TOP_K; // E

    void* args[] = { (void*)&h, (void*)&W, (void*)&bv, (void*)&ei, (void*)&E,
                     (void*)&s32, (void*)&ss, (void*)&si, (void*)&hist,
                     (void*)&bits, (void*)&offs, (void*)&cursor, (void*)&chunkSum,
                     (void*)&out_newh, (void*)&out_ids, (void*)&out_mask };

    hipError_t err = hipLaunchCooperativeKernel(mega_kernel, dim3(GRID), dim3(256),
                                                args, 0, stream);
    if (err != hipSuccess) {
        // fallback: proven multi-launch pipeline (same device logic)
        hipMemsetAsync(ws + 1200000, 0, 274944, stream);    // hist + bits
        f_score<<<N_NODES / 32, 256, 0, stream>>>(h, W, bv, s32, hist);
        f_scan<<<NCHUNK, 256, 0, stream>>>(hist, offs, cursor, chunkSum);
        f_scatter<<<(N_NODES + 255) / 256, 256, 0, stream>>>(s32, cursor, offs,
                                                             chunkSum, bits, ss, si);
        f_sort<<<NBINS / 256, 256, 0, stream>>>(offs, chunkSum, bits, ss, si);
        f_emit<<<TOP_K / 4, 256, 0, stream>>>(h, ss, si, out_newh, out_ids);
        f_edge<<<((E + 1) / 2 + 255) / 256, 256, 0, stream>>>(ei, bits, out_mask, E);
    }
}

// Round 3
// 245.800 us; speedup vs baseline: 3.0410x; 3.0410x over previous
//
#include <hip/hip_runtime.h>
#include <math.h>

#define N_NODES 100000
#define D_FEAT  256
#define TOP_K   50000
#define NBINS   65536
#define NCHUNK  64          // NBINS / 1024 chunks for the parallel scan
#define CUTPOS  (N_NODES - TOP_K)
#define ROWSTRIDE 260       // 256 + 4 pad: bank = (4g + l + 8i) % 32 -> 2-way = free
#define NBITW   3200        // member bitmask words (ceil(100000/32)=3125, padded)
#define FUSE_GRID   2048    // emit||edge fused kernel
#define EMIT_BLOCKS 1280    // split ~ bytes: emit 103 MB vs edge 64 MB

// Workspace layout (byte offsets, all 16B-aligned):
//         0 : s32      float[N_NODES]   (400,000)
//   400,000 : ss       float[N_NODES]   (400,000)  bucket-sorted scores
//   800,000 : si       int[N_NODES]     (400,000)  bucket-sorted node ids
// 1,200,000 : hist     int[NBINS]       (262,144)  } contiguous zero region
// 1,462,144 : bits     uint[NBITW]      ( 12,800)  } (274,944 B memset)
// 1,562,144 : offs     int[NBINS]       (262,144)  chunk-LOCAL exclusive offsets
// 1,824,288 : cursor   int[NBINS]       (262,144)
// 2,086,432 : chunkSum int[NCHUNK]      (256)

__device__ __forceinline__ int bucket_of(float s) {
    int b = (int)(s * 65536.0f);
    return min(max(b, 0), NBINS - 1);
}

// numpy SIMD float32 exp (FMA universal-intrinsics path) — bit-exact, verified R6.
__device__ __forceinline__ float np_expf(float x) {
    float q  = rintf(x * 1.44269504088896341f);
    float xr = fmaf(-q, 0.693359375f, x);
    xr       = fmaf(-q, -2.12194440e-4f, xr);
    float x2 = xr * xr;
    float p  = 1.9875691500E-4f;
    p = fmaf(p, xr, 1.3981999507E-3f);
    p = fmaf(p, xr, 8.3334519073E-3f);
    p = fmaf(p, xr, 4.1665795894E-2f);
    p = fmaf(p, xr, 1.6666665459E-1f);
    p = fmaf(p, xr, 5.0000001201E-1f);
    p = fmaf(p, x2, xr);
    p = p + 1.0f;
    return ldexpf(p, (int)q);
}

// OpenBLAS sgemv_t emulation, parallelized 8 lanes/node (bit-exact numerics):
// lane 8g+l runs chain l (k = i*8+l, i=0..31, serial fmaf) for node g of its wave;
// merge via shfl_xor 1,2,4 reproduces ((a0+a1)+(a2+a3))+((a4+a5)+(a6+a7)).
// Block = 256 thr = 4 waves = 32 nodes; rows staged to LDS coalesced.
// DO NOT TOUCH the numerics: bit-exact scores gate the top-k tie boundary.
__global__ void score_kernel(const float* __restrict__ h,
                             const float* __restrict__ W,
                             const float* __restrict__ bvec,
                             float* __restrict__ s32,
                             int* __restrict__ hist) {
    __shared__ float rows[32 * ROWSTRIDE];   // 33,280 B
    __shared__ float wl[256];
    int tid  = threadIdx.x;
    int wave = tid >> 6;
    int lane = tid & 63;
    int g    = lane >> 3;    // node within wave's 8
    int l    = lane & 7;     // chain id

    wl[tid] = W[tid];

    // stage this wave's 8 rows: one float4 per lane per row, coalesced 1KB
    int nodeBase = blockIdx.x * 32 + wave * 8;
#pragma unroll
    for (int r = 0; r < 8; ++r) {
        float4 v = ((const float4*)(h + (size_t)(nodeBase + r) * D_FEAT))[lane];
        *((float4*)&rows[(wave * 8 + r) * ROWSTRIDE + lane * 4]) = v;
    }
    __syncthreads();

    // W chain-slice into registers: wreg[i] = W[i*8 + l] (8-way LDS broadcast, free)
    float wreg[32];
#pragma unroll
    for (int i = 0; i < 32; ++i) wreg[i] = wl[i * 8 + l];

    // serial chain: acc = sum_{i} h[node][i*8+l] * W[i*8+l], strict fmaf order
    const float* myrow = &rows[(wave * 8 + g) * ROWSTRIDE];
    float acc = 0.0f;
#pragma unroll
    for (int i = 0; i < 32; ++i)
        acc = fmaf(myrow[i * 8 + l], wreg[i], acc);

    // vhaddps-style adjacent-pairwise merge tree (lane 8g+0 holds node g's z)
    float b01 = acc + __shfl_xor(acc, 1, 64);
    float b23 = b01 + __shfl_xor(b01, 2, 64);
    float z   = b23 + __shfl_xor(b23, 4, 64);

    z = z + bvec[0];
    float t = np_expf(-z);
    float s = 1.0f / (1.0f + t);       // IEEE f32 divide

    if (l == 0) {
        int node = nodeBase + g;
        s32[node] = s;
        atomicAdd(&hist[bucket_of(s)], 1);
    }
}

// Parallel chunk scan: 64 blocks x 256 threads, 4 consecutive bins per thread
// (int4 coalesced). Chunk-LOCAL exclusive offsets into offs+cursor, chunk total
// into chunkSum. Global base recomputed in-register by consumer blocks (free).
__global__ void scan_chunks_kernel(const int* __restrict__ hist,
                                   int* __restrict__ offs,
                                   int* __restrict__ cursor,
                                   int* __restrict__ chunkSum) {
    __shared__ int wsum[4];
    int tid  = threadIdx.x;
    int lane = tid & 63;
    int wid  = tid >> 6;
    int base = blockIdx.x * 1024 + tid * 4;

    int4 hv = *((const int4*)(hist + base));
    int e1 = hv.x;
    int e2 = hv.x + hv.y;
    int e3 = e2 + hv.z;
    int tot = e3 + hv.w;

    int incl = tot;
#pragma unroll
    for (int d = 1; d < 64; d <<= 1) {
        int t = __shfl_up(incl, d, 64);
        if (lane >= d) incl += t;
    }
    if (lane == 63) wsum[wid] = incl;
    __syncthreads();
    int wbase = 0;
#pragma unroll
    for (int w = 0; w < 3; ++w)
        if (w < wid) wbase += wsum[w];

    int excl = wbase + (incl - tot);
    int4 ov = make_int4(excl, excl + e1, excl + e2, excl + e3);
    *((int4*)(offs + base))   = ov;
    *((int4*)(cursor + base)) = ov;
    if (tid == 255) chunkSum[blockIdx.x] = excl + tot;
}

// wave-0: exclusive scan of the 64 chunk totals -> sbase (LDS)
__device__ __forceinline__ void build_base(const int* __restrict__ chunkSum,
                                           int* sbase, int tid) {
    if (tid < 64) {
        int v = chunkSum[tid];
        int inc = v;
#pragma unroll
        for (int d = 1; d < 64; d <<= 1) {
            int t = __shfl_up(inc, d, 64);
            if (tid >= d) inc += t;
        }
        sbase[tid] = inc - v;
    }
}

// Scatter + sure-member marking: buckets whose global start >= CUTPOS are
// entirely inside the top-k -> mark member bit now (removes emit->edge dep).
__global__ void scatter_kernel(const float* __restrict__ s32,
                               int* __restrict__ cursor,
                               const int* __restrict__ offs,
                               const int* __restrict__ chunkSum,
                               unsigned int* __restrict__ bits,
                               float* __restrict__ ss,
                               int* __restrict__ si) {
    __shared__ int sbase[64];
    int tid = threadIdx.x;
    build_base(chunkSum, sbase, tid);
    __syncthreads();
    int i = blockIdx.x * 256 + tid;
    if (i >= N_NODES) return;
    float s = s32[i];
    int b = bucket_of(s);
    int pos = atomicAdd(&cursor[b], 1);       // chunk-local position
    int gbase = sbase[b >> 10];
    ss[gbase + pos] = s;
    si[gbase + pos] = i;
    if (gbase + offs[b] >= CUTPOS)
        atomicOr(&bits[(unsigned)i >> 5], 1u << (i & 31));
}

// One thread per bucket; insertion sort ascending by (s asc, idx desc)
// so reversed (descending) order is (s desc, idx asc) — lax.top_k tie rule.
// Buckets entirely below the cut are never read -> skip. The (single)
// boundary bucket marks its suffix's member bits after sorting.
__global__ void bucket_sort_kernel(const int* __restrict__ offs,
                                   const int* __restrict__ chunkSum,
                                   unsigned int* __restrict__ bits,
                                   float* __restrict__ ss,
                                   int* __restrict__ si) {
    __shared__ int sbase[64];
    int tid = threadIdx.x;
    build_base(chunkSum, sbase, tid);
    __syncthreads();
    int b = blockIdx.x * 256 + tid;
    int s0 = sbase[b >> 10] + offs[b];
    int e  = (b == NBINS - 1) ? N_NODES : sbase[(b + 1) >> 10] + offs[b + 1];
    if (e <= CUTPOS) return;
    for (int i = s0 + 1; i < e; ++i) {
        float ks = ss[i];
        int   ki = si[i];
        int j = i - 1;
        while (j >= s0) {
            float ps = ss[j];
            int   pi = si[j];
            bool gt = (ps > ks) || (ps == ks && pi < ki);
            if (!gt) break;
            ss[j + 1] = ps;
            si[j + 1] = pi;
            --j;
        }
        ss[j + 1] = ks;
        si[j + 1] = ki;
    }
    if (s0 < CUTPOS) {                        // boundary bucket: mark suffix
        for (int i = CUTPOS; i < e; ++i) {
            int id = si[i];
            atomicOr(&bits[(unsigned)id >> 5], 1u << (id & 31));
        }
    }
}

__device__ __forceinline__ unsigned mem_bit(const unsigned int* __restrict__ bits,
                                            int s) {
    return (bits[(unsigned)s >> 5] >> (s & 31)) & 1u;
}

// Fused emit||edge: blocks 0..EMIT_BLOCKS-1 gather+scale top-k rows (grid-
// stride, 4 rows/block/iter); remaining blocks compute the edge mask (grid-
// stride over edge pairs, int4/int2 loads, member bitmask is L2-hot 12.5 KB).
__global__ void emit_edge_kernel(const float* __restrict__ h,
                                 const float* __restrict__ ss,
                                 const int* __restrict__ si,
                                 const int* __restrict__ ei,
                                 const unsigned int* __restrict__ bits,
                                 float* __restrict__ out_newh,
                                 float* __restrict__ out_ids,
                                 float* __restrict__ out_mask,
                                 int E) {
    int tid = threadIdx.x;
    int bid = blockIdx.x;

    if (bid < EMIT_BLOCKS) {
        int lane = tid & 63;
        int wg   = bid * 4 + (tid >> 6);
        for (int row = wg; row < TOP_K; row += EMIT_BLOCKS * 4) {
            int p = N_NODES - 1 - row;
            int id  = si[p];                  // wave-uniform -> broadcast
            float s = ss[p];
            if (lane == 0) out_ids[row] = (float)id;
            const float4* hv = (const float4*)(h + (size_t)id * D_FEAT);
            float4 v = hv[lane];
            ((float4*)(out_newh + (size_t)row * D_FEAT))[lane] =
                make_float4(v.x * s, v.y * s, v.z * s, v.w * s);
        }
        return;
    }

    // ---- edge partition ----
    __shared__ int sflag;
    if (tid < 64) {                           // int64-vs-int32 storage detect
        int v = ei[2 * tid + 1];
        unsigned long long m = __ballot(v == 0);
        if (tid == 0) sflag = (m == ~0ULL) ? 1 : 0;
    }
    __syncthreads();
    int flag = sflag;

    int npairs = (E + 1) / 2;
    int stride = (FUSE_GRID - EMIT_BLOCKS) * 256;
    for (int k = (bid - EMIT_BLOCKS) * 256 + tid; k < npairs; k += stride) {
        int i0 = 2 * k;
        int i1 = i0 + 1;
        if (i1 < E) {
            int s0, d0, s1, d1;
            if (flag) {                    // int64 storage: value in even dword
                int4 a  = ((const int4*)ei)[k];
                int4 bq = ((const int4*)(ei + 2 * (size_t)E))[k];
                s0 = a.x;  s1 = a.z;
                d0 = bq.x; d1 = bq.z;
            } else {                       // int32 storage
                int2 a  = ((const int2*)ei)[k];
                int2 bq = ((const int2*)(ei + (size_t)E))[k];
                s0 = a.x;  s1 = a.y;
                d0 = bq.x; d1 = bq.y;
            }
            bool ok0 = ((unsigned)s0 < (unsigned)N_NODES) &&
                       ((unsigned)d0 < (unsigned)N_NODES) &&
                       mem_bit(bits, s0) && mem_bit(bits, d0);
            bool ok1 = ((unsigned)s1 < (unsigned)N_NODES) &&
                       ((unsigned)d1 < (unsigned)N_NODES) &&
                       mem_bit(bits, s1) && mem_bit(bits, d1);
            ((float2*)out_mask)[k] = make_float2(ok0 ? 1.0f : 0.0f,
                                                 ok1 ? 1.0f : 0.0f);
        } else {                           // odd-E tail (not hit for E=3.2M)
            int s0, d0;
            if (flag) { s0 = ei[2 * i0]; d0 = ei[2 * ((size_t)E + i0)]; }
            else      { s0 = ei[i0];     d0 = ei[(size_t)E + i0]; }
            bool ok0 = ((unsigned)s0 < (unsigned)N_NODES) &&
                       ((unsigned)d0 < (unsigned)N_NODES) &&
                       mem_bit(bits, s0) && mem_bit(bits, d0);
            out_mask[i0] = ok0 ? 1.0f : 0.0f;
        }
    }
}

extern "C" void kernel_launch(void* const* d_in, const int* in_sizes, int n_in,
                              void* d_out, int out_size, void* d_ws, size_t ws_size,
                              hipStream_t stream) {
    const float* h  = (const float*)d_in[0];
    const float* W  = (const float*)d_in[1];
    const float* bv = (const float*)d_in[2];
    const int*   ei = (const int*)d_in[3];
    const int E = in_sizes[3] / 2;

    char* ws = (char*)d_ws;
    float*        s32      = (float*)(ws + 0);
    float*        ss       = (float*)(ws + 400000);
    int*          si       = (int*)(ws + 800000);
    int*          hist     = (int*)(ws + 1200000);
    unsigned int* bits     = (unsigned int*)(ws + 1462144);
    int*          offs     = (int*)(ws + 1562144);
    int*          cursor   = (int*)(ws + 1824288);
    int*          chunkSum = (int*)(ws + 2086432);

    float* out      = (float*)d_out;
    float* out_newh = out;                                  // TOP_K * D_FEAT
    float* out_ids  = out + (size_t)TOP_K * D_FEAT;         // TOP_K
    float* out_mask = out + (size_t)TOP_K * D_FEAT + TOP_K; // E

    hipMemsetAsync(ws + 1200000, 0, 274944, stream);        // hist + bits

    score_kernel<<<N_NODES / 32, 256, 0, stream>>>(h, W, bv, s32, hist);
    scan_chunks_kernel<<<NCHUNK, 256, 0, stream>>>(hist, offs, cursor, chunkSum);
    scatter_kernel<<<(N_NODES + 255) / 256, 256, 0, stream>>>(s32, cursor, offs,
                                                              chunkSum, bits, ss, si);
    bucket_sort_kernel<<<NBINS / 256, 256, 0, stream>>>(offs, chunkSum, bits, ss, si);
    emit_edge_kernel<<<FUSE_GRID, 256, 0, stream>>>(h, ss, si, ei, bits,
                                                    out_newh, out_ids, out_mask, E);
}

// Round 4
// 238.672 us; speedup vs baseline: 3.1318x; 1.0299x over previous
//
#include <hip/hip_runtime.h>
#include <math.h>

#define N_NODES 100000
#define D_FEAT  256
#define TOP_K   50000
#define NBINS   65536
#define NCHUNK  64          // NBINS / 1024 chunks for the parallel scan
#define CUTPOS  (N_NODES - TOP_K)
#define ROWSTRIDE 260       // 256 + 4 pad: bank = (4g + l + 8i) % 32 -> 2-way = free
#define NBITW   3200        // member bitmask words (ceil(100000/32)=3125, padded)
#define FUSE_GRID   2048    // emit||edge fused kernel (exactly co-resident @8/CU)
#define EMIT_BLOCKS 1408    // split: emit random-gather ~5.5TB/s vs edge stream ~6.5
                            // t_emit=103MB/(0.6875*5.5) ~= t_edge=64MB/(0.3125*6.5)

// Workspace layout (byte offsets, all 16B-aligned):
//         0 : s32      float[N_NODES]   (400,000)
//   400,000 : ss       float[N_NODES]   (400,000)  bucket-sorted scores
//   800,000 : si       int[N_NODES]     (400,000)  bucket-sorted node ids
// 1,200,000 : hist     int[NBINS]       (262,144)  } contiguous zero region
// 1,462,144 : bits     uint[NBITW]      ( 12,800)  } (274,944 B memset)
// 1,562,144 : offs     int[NBINS]       (262,144)  chunk-LOCAL exclusive offsets
// 1,824,288 : cursor   int[NBINS]       (262,144)
// 2,086,432 : chunkSum int[NCHUNK]      (256)

__device__ __forceinline__ int bucket_of(float s) {
    int b = (int)(s * 65536.0f);
    return min(max(b, 0), NBINS - 1);
}

// numpy SIMD float32 exp (FMA universal-intrinsics path) — bit-exact, verified R6.
__device__ __forceinline__ float np_expf(float x) {
    float q  = rintf(x * 1.44269504088896341f);
    float xr = fmaf(-q, 0.693359375f, x);
    xr       = fmaf(-q, -2.12194440e-4f, xr);
    float x2 = xr * xr;
    float p  = 1.9875691500E-4f;
    p = fmaf(p, xr, 1.3981999507E-3f);
    p = fmaf(p, xr, 8.3334519073E-3f);
    p = fmaf(p, xr, 4.1665795894E-2f);
    p = fmaf(p, xr, 1.6666665459E-1f);
    p = fmaf(p, xr, 5.0000001201E-1f);
    p = fmaf(p, x2, xr);
    p = p + 1.0f;
    return ldexpf(p, (int)q);
}

// OpenBLAS sgemv_t emulation, parallelized 8 lanes/node (bit-exact numerics):
// lane 8g+l runs chain l (k = i*8+l, i=0..31, serial fmaf) for node g of its wave;
// merge via shfl_xor 1,2,4 reproduces ((a0+a1)+(a2+a3))+((a4+a5)+(a6+a7)).
// Block = 256 thr = 4 waves = 32 nodes; rows staged to LDS coalesced.
// DO NOT TOUCH the numerics: bit-exact scores gate the top-k tie boundary.
__global__ void score_kernel(const float* __restrict__ h,
                             const float* __restrict__ W,
                             const float* __restrict__ bvec,
                             float* __restrict__ s32,
                             int* __restrict__ hist) {
    __shared__ float rows[32 * ROWSTRIDE];   // 33,280 B
    __shared__ float wl[256];
    int tid  = threadIdx.x;
    int wave = tid >> 6;
    int lane = tid & 63;
    int g    = lane >> 3;    // node within wave's 8
    int l    = lane & 7;     // chain id

    wl[tid] = W[tid];

    // stage this wave's 8 rows: one float4 per lane per row, coalesced 1KB
    int nodeBase = blockIdx.x * 32 + wave * 8;
#pragma unroll
    for (int r = 0; r < 8; ++r) {
        float4 v = ((const float4*)(h + (size_t)(nodeBase + r) * D_FEAT))[lane];
        *((float4*)&rows[(wave * 8 + r) * ROWSTRIDE + lane * 4]) = v;
    }
    __syncthreads();

    // W chain-slice into registers: wreg[i] = W[i*8 + l] (8-way LDS broadcast, free)
    float wreg[32];
#pragma unroll
    for (int i = 0; i < 32; ++i) wreg[i] = wl[i * 8 + l];

    // serial chain: acc = sum_{i} h[node][i*8+l] * W[i*8+l], strict fmaf order
    const float* myrow = &rows[(wave * 8 + g) * ROWSTRIDE];
    float acc = 0.0f;
#pragma unroll
    for (int i = 0; i < 32; ++i)
        acc = fmaf(myrow[i * 8 + l], wreg[i], acc);

    // vhaddps-style adjacent-pairwise merge tree (lane 8g+0 holds node g's z)
    float b01 = acc + __shfl_xor(acc, 1, 64);
    float b23 = b01 + __shfl_xor(b01, 2, 64);
    float z   = b23 + __shfl_xor(b23, 4, 64);

    z = z + bvec[0];
    float t = np_expf(-z);
    float s = 1.0f / (1.0f + t);       // IEEE f32 divide

    if (l == 0) {
        int node = nodeBase + g;
        s32[node] = s;
        atomicAdd(&hist[bucket_of(s)], 1);
    }
}

// Parallel chunk scan: 64 blocks x 256 threads, 4 consecutive bins per thread
// (int4 coalesced). Chunk-LOCAL exclusive offsets into offs+cursor, chunk total
// into chunkSum. Global base recomputed in-register by consumer blocks (free).
__global__ void scan_chunks_kernel(const int* __restrict__ hist,
                                   int* __restrict__ offs,
                                   int* __restrict__ cursor,
                                   int* __restrict__ chunkSum) {
    __shared__ int wsum[4];
    int tid  = threadIdx.x;
    int lane = tid & 63;
    int wid  = tid >> 6;
    int base = blockIdx.x * 1024 + tid * 4;

    int4 hv = *((const int4*)(hist + base));
    int e1 = hv.x;
    int e2 = hv.x + hv.y;
    int e3 = e2 + hv.z;
    int tot = e3 + hv.w;

    int incl = tot;
#pragma unroll
    for (int d = 1; d < 64; d <<= 1) {
        int t = __shfl_up(incl, d, 64);
        if (lane >= d) incl += t;
    }
    if (lane == 63) wsum[wid] = incl;
    __syncthreads();
    int wbase = 0;
#pragma unroll
    for (int w = 0; w < 3; ++w)
        if (w < wid) wbase += wsum[w];

    int excl = wbase + (incl - tot);
    int4 ov = make_int4(excl, excl + e1, excl + e2, excl + e3);
    *((int4*)(offs + base))   = ov;
    *((int4*)(cursor + base)) = ov;
    if (tid == 255) chunkSum[blockIdx.x] = excl + tot;
}

// wave-0: exclusive scan of the 64 chunk totals -> sbase (LDS)
__device__ __forceinline__ void build_base(const int* __restrict__ chunkSum,
                                           int* sbase, int tid) {
    if (tid < 64) {
        int v = chunkSum[tid];
        int inc = v;
#pragma unroll
        for (int d = 1; d < 64; d <<= 1) {
            int t = __shfl_up(inc, d, 64);
            if (tid >= d) inc += t;
        }
        sbase[tid] = inc - v;
    }
}

// Scatter + sure-member marking.
//  - Buckets whose global END <= CUTPOS are never read downstream (sort skips
//    them, emit reads positions >= CUTPOS only): skip the cursor atomic AND
//    the ss/si writes entirely (~half the scatter work).
//  - Buckets whose global START >= CUTPOS are fully inside the top-k: mark
//    member bit now (removes the emit->edge ordering dependency).
__global__ void scatter_kernel(const float* __restrict__ s32,
                               int* __restrict__ cursor,
                               const int* __restrict__ offs,
                               const int* __restrict__ chunkSum,
                               unsigned int* __restrict__ bits,
                               float* __restrict__ ss,
                               int* __restrict__ si) {
    __shared__ int sbase[64];
    int tid = threadIdx.x;
    build_base(chunkSum, sbase, tid);
    __syncthreads();
    int i = blockIdx.x * 256 + tid;
    if (i >= N_NODES) return;
    float s = s32[i];
    int b = bucket_of(s);
    int bn = b + 1;
    int gend = (bn == NBINS) ? N_NODES : sbase[bn >> 10] + offs[bn];
    if (gend <= CUTPOS) return;               // fully below cut: never read
    int pos = atomicAdd(&cursor[b], 1);       // chunk-local position
    int gbase = sbase[b >> 10];
    ss[gbase + pos] = s;
    si[gbase + pos] = i;
    if (gbase + offs[b] >= CUTPOS)            // fully above cut: sure member
        atomicOr(&bits[(unsigned)i >> 5], 1u << (i & 31));
}

// One thread per bucket; insertion sort ascending by (s asc, idx desc)
// so reversed (descending) order is (s desc, idx asc) — lax.top_k tie rule.
// Buckets entirely below the cut are never read -> skip. The (single)
// boundary bucket marks its suffix's member bits after sorting.
__global__ void bucket_sort_kernel(const int* __restrict__ offs,
                                   const int* __restrict__ chunkSum,
                                   unsigned int* __restrict__ bits,
                                   float* __restrict__ ss,
                                   int* __restrict__ si) {
    __shared__ int sbase[64];
    int tid = threadIdx.x;
    build_base(chunkSum, sbase, tid);
    __syncthreads();
    int b = blockIdx.x * 256 + tid;
    int s0 = sbase[b >> 10] + offs[b];
    int e  = (b == NBINS - 1) ? N_NODES : sbase[(b + 1) >> 10] + offs[b + 1];
    if (e <= CUTPOS) return;
    for (int i = s0 + 1; i < e; ++i) {
        float ks = ss[i];
        int   ki = si[i];
        int j = i - 1;
        while (j >= s0) {
            float ps = ss[j];
            int   pi = si[j];
            bool gt = (ps > ks) || (ps == ks && pi < ki);
            if (!gt) break;
            ss[j + 1] = ps;
            si[j + 1] = pi;
            --j;
        }
        ss[j + 1] = ks;
        si[j + 1] = ki;
    }
    if (s0 < CUTPOS) {                        // boundary bucket: mark suffix
        for (int i = CUTPOS; i < e; ++i) {
            int id = si[i];
            atomicOr(&bits[(unsigned)id >> 5], 1u << (id & 31));
        }
    }
}

__device__ __forceinline__ unsigned mem_bit(const unsigned int* __restrict__ bits,
                                            int s) {
    return (bits[(unsigned)s >> 5] >> (s & 31)) & 1u;
}

// Fused emit||edge: blocks 0..EMIT_BLOCKS-1 gather+scale top-k rows (grid-
// stride, 4 rows/block/iter); remaining blocks compute the edge mask (grid-
// stride over edge pairs, int4/int2 loads, member bitmask is L1-hot 12.5 KB).
__global__ void emit_edge_kernel(const float* __restrict__ h,
                                 const float* __restrict__ ss,
                                 const int* __restrict__ si,
                                 const int* __restrict__ ei,
                                 const unsigned int* __restrict__ bits,
                                 float* __restrict__ out_newh,
                                 float* __restrict__ out_ids,
                                 float* __restrict__ out_mask,
                                 int E) {
    int tid = threadIdx.x;
    int bid = blockIdx.x;

    if (bid < EMIT_BLOCKS) {
        int lane = tid & 63;
        int wg   = bid * 4 + (tid >> 6);
        for (int row = wg; row < TOP_K; row += EMIT_BLOCKS * 4) {
            int p = N_NODES - 1 - row;
            int id  = si[p];                  // wave-uniform -> broadcast
            float s = ss[p];
            if (lane == 0) out_ids[row] = (float)id;
            const float4* hv = (const float4*)(h + (size_t)id * D_FEAT);
            float4 v = hv[lane];
            ((float4*)(out_newh + (size_t)row * D_FEAT))[lane] =
                make_float4(v.x * s, v.y * s, v.z * s, v.w * s);
        }
        return;
    }

    // ---- edge partition ----
    __shared__ int sflag;
    if (tid < 64) {                           // int64-vs-int32 storage detect
        int v = ei[2 * tid + 1];
        unsigned long long m = __ballot(v == 0);
        if (tid == 0) sflag = (m == ~0ULL) ? 1 : 0;
    }
    __syncthreads();
    int flag = sflag;

    int npairs = (E + 1) / 2;
    int stride = (FUSE_GRID - EMIT_BLOCKS) * 256;
    for (int k = (bid - EMIT_BLOCKS) * 256 + tid; k < npairs; k += stride) {
        int i0 = 2 * k;
        int i1 = i0 + 1;
        if (i1 < E) {
            int s0, d0, s1, d1;
            if (flag) {                    // int64 storage: value in even dword
                int4 a  = ((const int4*)ei)[k];
                int4 bq = ((const int4*)(ei + 2 * (size_t)E))[k];
                s0 = a.x;  s1 = a.z;
                d0 = bq.x; d1 = bq.z;
            } else {                       // int32 storage
                int2 a  = ((const int2*)ei)[k];
                int2 bq = ((const int2*)(ei + (size_t)E))[k];
                s0 = a.x;  s1 = a.y;
                d0 = bq.x; d1 = bq.y;
            }
            bool ok0 = ((unsigned)s0 < (unsigned)N_NODES) &&
                       ((unsigned)d0 < (unsigned)N_NODES) &&
                       mem_bit(bits, s0) && mem_bit(bits, d0);
            bool ok1 = ((unsigned)s1 < (unsigned)N_NODES) &&
                       ((unsigned)d1 < (unsigned)N_NODES) &&
                       mem_bit(bits, s1) && mem_bit(bits, d1);
            ((float2*)out_mask)[k] = make_float2(ok0 ? 1.0f : 0.0f,
                                                 ok1 ? 1.0f : 0.0f);
        } else {                           // odd-E tail (not hit for E=3.2M)
            int s0, d0;
            if (flag) { s0 = ei[2 * i0]; d0 = ei[2 * ((size_t)E + i0)]; }
            else      { s0 = ei[i0];     d0 = ei[(size_t)E + i0]; }
            bool ok0 = ((unsigned)s0 < (unsigned)N_NODES) &&
                       ((unsigned)d0 < (unsigned)N_NODES) &&
                       mem_bit(bits, s0) && mem_bit(bits, d0);
            out_mask[i0] = ok0 ? 1.0f : 0.0f;
        }
    }
}

extern "C" void kernel_launch(void* const* d_in, const int* in_sizes, int n_in,
                              void* d_out, int out_size, void* d_ws, size_t ws_size,
                              hipStream_t stream) {
    const float* h  = (const float*)d_in[0];
    const float* W  = (const float*)d_in[1];
    const float* bv = (const float*)d_in[2];
    const int*   ei = (const int*)d_in[3];
    const int E = in_sizes[3] / 2;

    char* ws = (char*)d_ws;
    float*        s32      = (float*)(ws + 0);
    float*        ss       = (float*)(ws + 400000);
    int*          si       = (int*)(ws + 800000);
    int*          hist     = (int*)(ws + 1200000);
    unsigned int* bits     = (unsigned int*)(ws + 1462144);
    int*          offs     = (int*)(ws + 1562144);
    int*          cursor   = (int*)(ws + 1824288);
    int*          chunkSum = (int*)(ws + 2086432);

    float* out      = (float*)d_out;
    float* out_newh = out;                                  // TOP_K * D_FEAT
    float* out_ids  = out + (size_t)TOP_K * D_FEAT;         // TOP_K
    float* out_mask = out + (size_t)TOP_K * D_FEAT + TOP_K; // E

    hipMemsetAsync(ws + 1200000, 0, 274944, stream);        // hist + bits

    score_kernel<<<N_NODES / 32, 256, 0, stream>>>(h, W, bv, s32, hist);
    scan_chunks_kernel<<<NCHUNK, 256, 0, stream>>>(hist, offs, cursor, chunkSum);
    scatter_kernel<<<(N_NODES + 255) / 256, 256, 0, stream>>>(s32, cursor, offs,
                                                              chunkSum, bits, ss, si);
    bucket_sort_kernel<<<NBINS / 256, 256, 0, stream>>>(offs, chunkSum, bits, ss, si);
    emit_edge_kernel<<<FUSE_GRID, 256, 0, stream>>>(h, ss, si, ei, bits,
                                                    out_newh, out_ids, out_mask, E);
}